// Round 15
// baseline (186.569 us; speedup 1.0000x reference)
//
#include <hip/hip_runtime.h>

#define N_TOK 4096
#define E_DIM 1024
#define NH    16
#define HD    64

typedef __bf16 bf16x8 __attribute__((ext_vector_type(8)));
typedef __bf16 bf16x4 __attribute__((ext_vector_type(4)));
typedef float  f32x4  __attribute__((ext_vector_type(4)));
typedef float  f32x16 __attribute__((ext_vector_type(16)));

#define GLOAD16(gsrc, ldst) __builtin_amdgcn_global_load_lds( \
    (const __attribute__((address_space(1))) void*)(gsrc),    \
    (__attribute__((address_space(3))) void*)(ldst), 16, 0, 0)

__device__ __forceinline__ f32x16 zero16() {
    f32x16 z;
#pragma unroll
    for (int i = 0; i < 16; ++i) z[i] = 0.f;
    return z;
}

__device__ __forceinline__ unsigned pk2(float a, float b) {
    union { __bf16 h[2]; unsigned u; } t;
    t.h[0] = (__bf16)a; t.h[1] = (__bf16)b;
    return t.u;
}

__device__ __forceinline__ float fmax3(float a, float b, float c) {
    return fmaxf(fmaxf(a, b), c);   // clang fuses to v_max3_f32
}

__device__ __forceinline__ void cvt8(const float* __restrict__ src, __bf16* __restrict__ dst, int i) {
    const float4 a = ((const float4*)src)[i * 2];
    const float4 b = ((const float4*)src)[i * 2 + 1];
    ((bf16x8*)dst)[i] = bf16x8{(__bf16)a.x, (__bf16)a.y, (__bf16)a.z, (__bf16)a.w,
                               (__bf16)b.x, (__bf16)b.y, (__bf16)b.z, (__bf16)b.w};
}

// ---------- kernel 0a: fused fp32->bf16 convert for x, wqkv, wproj ----------
__global__ __launch_bounds__(256) void conv_tri(const float* __restrict__ s1, __bf16* __restrict__ d1, int n1,
                                                const float* __restrict__ s2, __bf16* __restrict__ d2, int n2,
                                                const float* __restrict__ s3, __bf16* __restrict__ d3, int n3) {
    const int i = blockIdx.x * 256 + threadIdx.x;
    if (i < n1)                 cvt8(s1, d1, i);
    else if (i < n1 + n2)       cvt8(s2, d2, i - n1);
    else if (i < n1 + n2 + n3)  cvt8(s3, d3, i - n1 - n2);
}

// ---------- kernel 0b: pair convert (fallback when ws too small for separate Wp) ----------
__global__ __launch_bounds__(256) void conv_pair(const float* __restrict__ s1, __bf16* __restrict__ d1, int n1,
                                                 const float* __restrict__ s2, __bf16* __restrict__ d2, int n2) {
    const int i = blockIdx.x * 256 + threadIdx.x;
    if (i < n1)            cvt8(s1, d1, i);
    else if (i < n1 + n2)  cvt8(s2, d2, i - n1);
}

__global__ __launch_bounds__(256) void conv_bf16(const float* __restrict__ src,
                                                 __bf16* __restrict__ dst, int n8) {
    const int i = blockIdx.x * 256 + threadIdx.x;
    if (i >= n8) return;
    cvt8(src, dst, i);
}

// ---------- shared GEMM core (m97 structure): 128x128 tile, BK=32, global_load_lds ----------
__device__ __forceinline__ void gemm_core(const __bf16* __restrict__ A, const __bf16* __restrict__ B,
                                          const int K, const int rowBase, const int colBase,
                                          __bf16* As, __bf16* Bs, f32x4 (&acc)[4][4]) {
    const int tid = threadIdx.x, lane = tid & 63, wid = tid >> 6;
    const int wm = wid >> 1, wn = wid & 1;
    const int lr = lane & 15, lg = lane >> 4;
    const int lrow = lane >> 2, lcol = (lane & 3) * 8;

    const __bf16* aBase = A + (size_t)(rowBase + wid * 16 + lrow) * K + lcol;
    const __bf16* bBase = B + (size_t)(colBase + wid * 16 + lrow) * K + lcol;
    const size_t row64 = (size_t)64 * K;

    for (int kt = 0; kt < K; kt += 32) {
        __syncthreads();
        GLOAD16(aBase + kt,         As + wid * 512);
        GLOAD16(aBase + row64 + kt, As + 2048 + wid * 512);
        GLOAD16(bBase + kt,         Bs + wid * 512);
        GLOAD16(bBase + row64 + kt, Bs + 2048 + wid * 512);
        __syncthreads();

        bf16x8 af[4], bfr[4];
#pragma unroll
        for (int i = 0; i < 4; ++i) {
            af[i]  = *(const bf16x8*)&As[(wm * 64 + i * 16 + lr) * 32 + lg * 8];
            bfr[i] = *(const bf16x8*)&Bs[(wn * 64 + i * 16 + lr) * 32 + lg * 8];
        }
#pragma unroll
        for (int i = 0; i < 4; ++i)
#pragma unroll
            for (int j = 0; j < 4; ++j)
                acc[i][j] = __builtin_amdgcn_mfma_f32_16x16x32_bf16(af[i], bfr[j], acc[i][j], 0, 0, 0);
    }
}

// ---------- kernel 1: QKV projection; Q,K row-major [h][n][d], V transposed+k-slot-permuted ----------
#define QSCALE 0.180336879f   // 1/sqrt(64) * log2(e)

__global__ __launch_bounds__(256) void qkv_gemm(const __bf16* __restrict__ x,
                                                const __bf16* __restrict__ wqkv,
                                                const float* __restrict__ bqkv,
                                                __bf16* __restrict__ Qb,
                                                __bf16* __restrict__ Kb,
                                                __bf16* __restrict__ VtG) {
    __shared__ __bf16 As[128 * 32];
    __shared__ __bf16 Bs[128 * 32];
    f32x4 acc[4][4];
#pragma unroll
    for (int i = 0; i < 4; ++i)
#pragma unroll
        for (int j = 0; j < 4; ++j)
            acc[i][j] = f32x4{0.f, 0.f, 0.f, 0.f};

    // XCD-aware swizzle: 768 blocks, 96/XCD chunk -> B-panel L2 reuse
    const int lin = blockIdx.y * 32 + blockIdx.x;
    const int swz = (lin & 7) * 96 + (lin >> 3);
    const int tm = swz & 31, tn = swz >> 5;

    gemm_core(x, wqkv, E_DIM, tm * 128, tn * 128, As, Bs, acc);

    const int tid = threadIdx.x;
    const int lane = tid & 63, wid = tid >> 6;
    const int wm = wid >> 1, wn = wid & 1;
    const int lr = lane & 15, lg = lane >> 4;

#pragma unroll
    for (int ni = 0; ni < 4; ++ni) {
        const int f = tn * 128 + wn * 64 + ni * 16 + lr;   // 0..3071
        const float bias = bqkv[f];
        const int which = f >> 10;          // 0=Q 1=K 2=V (uniform per block)
        const int hh = (f & 1023) >> 6;
        const int dd = f & 63;
        if (which == 2) {
            __bf16* dst = VtG + ((size_t)hh * HD + dd) * N_TOK;
#pragma unroll
            for (int mi = 0; mi < 4; ++mi) {
                const int n0 = tm * 128 + wm * 64 + mi * 16 + lg * 4;
                const int pos = (n0 & ~12) | ((n0 & 4) << 1) | ((n0 & 8) >> 1);  // swap bits 2,3
                bf16x4 v;
#pragma unroll
                for (int r = 0; r < 4; ++r) v[r] = (__bf16)(acc[mi][ni][r] + bias);
                *(bf16x4*)&dst[pos] = v;
            }
        } else {
            __bf16* dst = (which == 0) ? Qb : Kb;
            const float sc = (which == 0) ? QSCALE : 1.0f;
#pragma unroll
            for (int mi = 0; mi < 4; ++mi) {
#pragma unroll
                for (int r = 0; r < 4; ++r) {
                    const int n = tm * 128 + wm * 64 + mi * 16 + lg * 4 + r;
                    dst[((size_t)hh * N_TOK + n) * HD + dd] = (__bf16)((acc[mi][ni][r] + bias) * sc);
                }
            }
        }
    }
}

// ---------- kernel 2: flash attention — L2-direct K/V (no LDS staging, no main-loop barriers) ----------
// K/V fragments are pure per-lane-row reads; K/V L2-resident per XCD (2 heads = 2MB of 4MB).
// LDS used only for the kv-half merge epilogue.
#define QBLK  256
#define KVB   128
#define NTILE (N_TOK / KVB)

__global__ __launch_bounds__(512, 2) void flash_attn(const __bf16* __restrict__ Qb,
                                                     const __bf16* __restrict__ Kb,
                                                     const __bf16* __restrict__ Vt,
                                                     __bf16* __restrict__ Ob) {
    __shared__ float scratch[17152];   // merge: 8 regions x (32q x 65) + 8 x 64  = 68608 B

    const int tid = threadIdx.x, lane = tid & 63, wid = tid >> 6;
    const int lq = lane & 31, hi = lane >> 5;
    const int qg = wid >> 1, hw = wid & 1;

    // XCD swizzle: 256 blocks, 32/XCD = 2 full heads' K/V resident per XCD L2
    const int lin = blockIdx.y * 16 + blockIdx.x;
    const int swz = (lin & 7) * 32 + (lin >> 3);
    const int qblk = swz & 15, h = swz >> 4;

    const __bf16* Qh = Qb + (size_t)h * N_TOK * HD;
    const __bf16* Kh = Kb + (size_t)h * N_TOK * HD;
    const __bf16* Vh = Vt + (size_t)h * HD * N_TOK;

    // Q B-frags for 2 q-subtiles: col=q=lq, k-slot (hi,j): d = sd*16 + hi*8 + j
    bf16x8 qf[2][4];
#pragma unroll
    for (int g = 0; g < 2; ++g) {
        const size_t qr = (size_t)qblk * QBLK + qg * 64 + g * 32 + lq;
#pragma unroll
        for (int sd = 0; sd < 4; ++sd)
            qf[g][sd] = *(const bf16x8*)&Qh[qr * HD + sd * 16 + hi * 8];
    }

    f32x16 o[2][2], lacc[2];
#pragma unroll
    for (int g = 0; g < 2; ++g) { o[g][0] = zero16(); o[g][1] = zero16(); lacc[g] = zero16(); }
    float m[2] = {-INFINITY, -INFINITY};

    const bf16x8 ones = bf16x8{(__bf16)1.f, (__bf16)1.f, (__bf16)1.f, (__bf16)1.f,
                               (__bf16)1.f, (__bf16)1.f, (__bf16)1.f, (__bf16)1.f};

    // per-lane row bases (advance per tile): K rows hw*64+lq and +32; V^T rows d=lq and d=32+lq
    const __bf16* kRow0 = Kh + (size_t)(hw * 64 + lq) * HD;
    const __bf16* kRow1 = kRow0 + (size_t)32 * HD;
    const __bf16* vRow0 = Vh + (size_t)lq * N_TOK + hw * 64;
    const __bf16* vRow1 = vRow0 + (size_t)32 * N_TOK;

    for (int t = 0; t < NTILE; ++t) {
        // K fragments straight from L2 (own row, contiguous 16B chunks)
        bf16x8 kf0[4], kf1[4];
#pragma unroll
        for (int sd = 0; sd < 4; ++sd) {
            kf0[sd] = *(const bf16x8*)(kRow0 + sd * 16 + hi * 8);
            kf1[sd] = *(const bf16x8*)(kRow1 + sd * 16 + hi * 8);
        }

        // S^T = K Q^T on this wave's 64-kv half, both q-subtiles share each kf
        f32x16 s[2][2];
#pragma unroll
        for (int g = 0; g < 2; ++g) { s[g][0] = zero16(); s[g][1] = zero16(); }
        __builtin_amdgcn_s_setprio(1);
#pragma unroll
        for (int sd = 0; sd < 4; ++sd) {
            s[0][0] = __builtin_amdgcn_mfma_f32_32x32x16_bf16(kf0[sd], qf[0][sd], s[0][0], 0, 0, 0);
            s[0][1] = __builtin_amdgcn_mfma_f32_32x32x16_bf16(kf1[sd], qf[0][sd], s[0][1], 0, 0, 0);
            s[1][0] = __builtin_amdgcn_mfma_f32_32x32x16_bf16(kf0[sd], qf[1][sd], s[1][0], 0, 0, 0);
            s[1][1] = __builtin_amdgcn_mfma_f32_32x32x16_bf16(kf1[sd], qf[1][sd], s[1][1], 0, 0, 0);
        }
        __builtin_amdgcn_s_setprio(0);

        // V fragments issued now — L2 latency hides under the softmax VALU chain
        bf16x8 vf0[4], vf1[4];
#pragma unroll
        for (int w = 0; w < 4; ++w) {
            vf0[w] = *(const bf16x8*)(vRow0 + w * 16 + hi * 8);
            vf1[w] = *(const bf16x8*)(vRow1 + w * 16 + hi * 8);
        }

        // per-q max: 3-ary tree (v_max3) over 32 in-lane values + cross-half shuffle
        float mx[2];
#pragma unroll
        for (int g = 0; g < 2; ++g) {
            const float t0 = fmax3(s[g][0][0],  s[g][0][1],  s[g][0][2]);
            const float t1 = fmax3(s[g][0][3],  s[g][0][4],  s[g][0][5]);
            const float t2 = fmax3(s[g][0][6],  s[g][0][7],  s[g][0][8]);
            const float t3 = fmax3(s[g][0][9],  s[g][0][10], s[g][0][11]);
            const float t4 = fmax3(s[g][0][12], s[g][0][13], s[g][0][14]);
            const float t5 = fmax3(s[g][1][0],  s[g][1][1],  s[g][1][2]);
            const float t6 = fmax3(s[g][1][3],  s[g][1][4],  s[g][1][5]);
            const float t7 = fmax3(s[g][1][6],  s[g][1][7],  s[g][1][8]);
            const float t8 = fmax3(s[g][1][9],  s[g][1][10], s[g][1][11]);
            const float t9 = fmax3(s[g][1][12], s[g][1][13], s[g][1][14]);
            const float u0 = fmax3(t0, t1, s[g][0][15]);
            const float u1 = fmax3(t2, t3, t4);
            const float u2 = fmax3(t5, t6, s[g][1][15]);
            const float u3 = fmax3(t7, t8, t9);
            float a = fmaxf(fmax3(u0, u1, u2), u3);
            mx[g] = fmaxf(a, __shfl_xor(a, 32));
        }

        // defer-max: rescale only when per-tile growth exceeds 2^8
        if (!__all(mx[0] <= m[0] + 8.f && mx[1] <= m[1] + 8.f)) {
#pragma unroll
            for (int g = 0; g < 2; ++g) {
                const float mn = fmaxf(m[g], mx[g]);
                const float al = __builtin_amdgcn_exp2f(m[g] - mn);
                m[g] = mn;
#pragma unroll
                for (int r = 0; r < 16; ++r) { o[g][0][r] *= al; o[g][1][r] *= al; }
                lacc[g][0] *= al;
            }
        }

        // per 16-k window: exp2 + pack own regs directly (V k-slot perm makes this exact)
#pragma unroll
        for (int w = 0; w < 4; ++w) {
            const int rb = (w & 1) * 8;
            const int half = (w < 2) ? 0 : 1;
            bf16x8 pfv[2];
#pragma unroll
            for (int g = 0; g < 2; ++g) {
                union { unsigned u[4]; bf16x8 v; } pf;
                pf.u[0] = pk2(__builtin_amdgcn_exp2f(s[g][half][rb + 0] - m[g]),
                              __builtin_amdgcn_exp2f(s[g][half][rb + 1] - m[g]));
                pf.u[1] = pk2(__builtin_amdgcn_exp2f(s[g][half][rb + 2] - m[g]),
                              __builtin_amdgcn_exp2f(s[g][half][rb + 3] - m[g]));
                pf.u[2] = pk2(__builtin_amdgcn_exp2f(s[g][half][rb + 4] - m[g]),
                              __builtin_amdgcn_exp2f(s[g][half][rb + 5] - m[g]));
                pf.u[3] = pk2(__builtin_amdgcn_exp2f(s[g][half][rb + 6] - m[g]),
                              __builtin_amdgcn_exp2f(s[g][half][rb + 7] - m[g]));
                pfv[g] = pf.v;
            }

            __builtin_amdgcn_s_setprio(1);
            o[0][0] = __builtin_amdgcn_mfma_f32_32x32x16_bf16(vf0[w], pfv[0], o[0][0], 0, 0, 0);
            o[0][1] = __builtin_amdgcn_mfma_f32_32x32x16_bf16(vf1[w], pfv[0], o[0][1], 0, 0, 0);
            o[1][0] = __builtin_amdgcn_mfma_f32_32x32x16_bf16(vf0[w], pfv[1], o[1][0], 0, 0, 0);
            o[1][1] = __builtin_amdgcn_mfma_f32_32x32x16_bf16(vf1[w], pfv[1], o[1][1], 0, 0, 0);
            lacc[0] = __builtin_amdgcn_mfma_f32_32x32x16_bf16(ones, pfv[0], lacc[0], 0, 0, 0);
            lacc[1] = __builtin_amdgcn_mfma_f32_32x32x16_bf16(ones, pfv[1], lacc[1], 0, 0, 0);
            __builtin_amdgcn_s_setprio(0);
        }

        kRow0 += (size_t)KVB * HD;
        kRow1 += (size_t)KVB * HD;
        vRow0 += KVB;
        vRow1 += KVB;
    }

    // ---- merge kv-half pairs through LDS, then epilogue (per q-subtile) ----
    if (hw == 1) {
#pragma unroll
        for (int g = 0; g < 2; ++g) {
            float* po = scratch + (qg * 2 + g) * 2080;
#pragma unroll
            for (int r = 0; r < 16; ++r) {
                const int d0 = (r & 3) + 8 * (r >> 2) + 4 * hi;
                po[lq * 65 + d0]      = o[g][0][r];
                po[lq * 65 + 32 + d0] = o[g][1][r];
            }
            if (hi == 0) {
                float* plm = scratch + 16640 + (qg * 2 + g) * 64;
                plm[lq * 2] = lacc[g][0]; plm[lq * 2 + 1] = m[g];
            }
        }
    }
    __syncthreads();
    if (hw == 0) {
#pragma unroll
        for (int g = 0; g < 2; ++g) {
            float* po  = scratch + (qg * 2 + g) * 2080;
            float* plm = scratch + 16640 + (qg * 2 + g) * 64;
            const float l1 = plm[lq * 2], m1 = plm[lq * 2 + 1];
            const float M  = fmaxf(m[g], m1);
            const float a0 = __builtin_amdgcn_exp2f(m[g] - M);
            const float a1 = __builtin_amdgcn_exp2f(m1 - M);
            const float inv = 1.0f / (lacc[g][0] * a0 + l1 * a1);
            const size_t qr = (size_t)qblk * QBLK + qg * 64 + g * 32 + lq;
            __bf16* obase = &Ob[qr * E_DIM + h * HD];
#pragma unroll
            for (int grp = 0; grp < 4; ++grp) {
                bf16x4 v0, v1;
#pragma unroll
                for (int c = 0; c < 4; ++c) {
                    const int r = grp * 4 + c;
                    const int d0 = c + 8 * grp + 4 * hi;
                    v0[c] = (__bf16)((o[g][0][r] * a0 + po[lq * 65 + d0]      * a1) * inv);
                    v1[c] = (__bf16)((o[g][1][r] * a0 + po[lq * 65 + 32 + d0] * a1) * inv);
                }
                *(bf16x4*)&obase[grp * 8 + hi * 4]      = v0;
                *(bf16x4*)&obase[32 + grp * 8 + hi * 4] = v1;
            }
        }
    }
}

// ---------- kernel 3: output projection, 64x128 tile, 512 blocks = 2/CU ----------
__global__ __launch_bounds__(256) void proj_gemm(const __bf16* __restrict__ Ob,
                                                 const __bf16* __restrict__ wp,
                                                 const float* __restrict__ bp,
                                                 float* __restrict__ out) {
    __shared__ __bf16 As[64 * 32];
    __shared__ __bf16 Bs[128 * 32];
    f32x4 acc[2][4];
#pragma unroll
    for (int i = 0; i < 2; ++i)
#pragma unroll
        for (int j = 0; j < 4; ++j)
            acc[i][j] = f32x4{0.f, 0.f, 0.f, 0.f};

    // XCD swizzle: 512 blocks, 64/XCD -> tn constant per XCD (B panel L2-resident)
    const int lin = blockIdx.y * 64 + blockIdx.x;
    const int swz = (lin & 7) * 64 + (lin >> 3);
    const int tm = swz & 63, tn = swz >> 6;

    const int tid = threadIdx.x, lane = tid & 63, wid = tid >> 6;
    const int wm = wid >> 1, wn = wid & 1;
    const int lr = lane & 15, lg = lane >> 4;
    const int lrow = lane >> 2, lcol = (lane & 3) * 8;

    const __bf16* aBase = Ob + (size_t)(tm * 64 + wid * 16 + lrow) * E_DIM + lcol;
    const __bf16* bBase = wp + (size_t)(tn * 128 + wid * 16 + lrow) * E_DIM + lcol;
    const size_t row64 = (size_t)64 * E_DIM;

    for (int kt = 0; kt < E_DIM; kt += 32) {
        __syncthreads();
        GLOAD16(aBase + kt,         As + wid * 512);
        GLOAD16(bBase + kt,         Bs + wid * 512);
        GLOAD16(bBase + row64 + kt, Bs + 2048 + wid * 512);
        __syncthreads();

        bf16x8 af[2], bfr[4];
#pragma unroll
        for (int i = 0; i < 2; ++i)
            af[i]  = *(const bf16x8*)&As[(wm * 32 + i * 16 + lr) * 32 + lg * 8];
#pragma unroll
        for (int j = 0; j < 4; ++j)
            bfr[j] = *(const bf16x8*)&Bs[(wn * 64 + j * 16 + lr) * 32 + lg * 8];
#pragma unroll
        for (int i = 0; i < 2; ++i)
#pragma unroll
            for (int j = 0; j < 4; ++j)
                acc[i][j] = __builtin_amdgcn_mfma_f32_16x16x32_bf16(af[i], bfr[j], acc[i][j], 0, 0, 0);
    }

#pragma unroll
    for (int ni = 0; ni < 4; ++ni) {
        const int f = tn * 128 + wn * 64 + ni * 16 + lr;
        const float bias = bp[f];
#pragma unroll
        for (int mi = 0; mi < 2; ++mi) {
#pragma unroll
            for (int r = 0; r < 4; ++r) {
                const int n = tm * 64 + wm * 32 + mi * 16 + lg * 4 + r;
                out[(size_t)n * E_DIM + f] = acc[mi][ni][r] + bias;
            }
        }
    }
}

// ---------- launch ----------
extern "C" void kernel_launch(void* const* d_in, const int* in_sizes, int n_in,
                              void* d_out, int out_size, void* d_ws, size_t ws_size,
                              hipStream_t stream) {
    const float* x     = (const float*)d_in[0];
    const float* wqkv  = (const float*)d_in[1];
    const float* bqkv  = (const float*)d_in[2];
    const float* wproj = (const float*)d_in[3];
    const float* bproj = (const float*)d_in[4];
    float* out = (float*)d_out;

    const size_t headElems = (size_t)NH * N_TOK * HD;      // 4.19M
    __bf16* Qb   = (__bf16*)d_ws;
    __bf16* Kb   = Qb + headElems;
    __bf16* VtG  = Kb + headElems;                         // [H][D][N'] (k-slot-permuted cols)
    __bf16* ObXb = VtG + headElems;                        // xb during qkv, then Ob
    __bf16* Wb   = ObXb + headElems;                       // wqkv-bf16 (3M elems)

    const int n1 = N_TOK * E_DIM / 8;           // 524288 (x)
    const int n2 = 3 * E_DIM * E_DIM / 8;       // 393216 (wqkv)
    const int n3 = E_DIM * E_DIM / 8;           // 131072 (wproj)

    const size_t needBytes = (4 * headElems + (size_t)(3 + 1) * E_DIM * E_DIM) * sizeof(__bf16);
    const bool sep = ws_size >= needBytes;
    __bf16* Wp = sep ? (Wb + (size_t)3 * E_DIM * E_DIM) : Wb;

    if (sep) {
        conv_tri<<<(n1 + n2 + n3 + 255) / 256, 256, 0, stream>>>(x, ObXb, n1, wqkv, Wb, n2, wproj, Wp, n3);
    } else {
        conv_pair<<<(n1 + n2 + 255) / 256, 256, 0, stream>>>(x, ObXb, n1, wqkv, Wb, n2);
    }

    qkv_gemm<<<dim3(N_TOK / 128, 3 * E_DIM / 128), 256, 0, stream>>>(ObXb, Wb, bqkv, Qb, Kb, VtG);

    if (!sep) {
        conv_bf16<<<(n3 + 255) / 256, 256, 0, stream>>>(wproj, Wp, n3);
    }

    flash_attn<<<dim3(N_TOK / QBLK, NH), 512, 0, stream>>>(Qb, Kb, VtG, ObXb);

    proj_gemm<<<dim3(N_TOK / 64, E_DIM / 128), 256, 0, stream>>>(ObXb, Wp, bproj, out);
}

// Round 16
// 152.885 us; speedup vs baseline: 1.2203x; 1.2203x over previous
//
#include <hip/hip_runtime.h>

#define N_TOK 4096
#define E_DIM 1024
#define NH    16
#define HD    64

typedef __bf16 bf16x8 __attribute__((ext_vector_type(8)));
typedef __bf16 bf16x4 __attribute__((ext_vector_type(4)));
typedef float  f32x4  __attribute__((ext_vector_type(4)));
typedef float  f32x16 __attribute__((ext_vector_type(16)));

#define GLOAD16(gsrc, ldst) __builtin_amdgcn_global_load_lds( \
    (const __attribute__((address_space(1))) void*)(gsrc),    \
    (__attribute__((address_space(3))) void*)(ldst), 16, 0, 0)

__device__ __forceinline__ f32x16 zero16() {
    f32x16 z;
#pragma unroll
    for (int i = 0; i < 16; ++i) z[i] = 0.f;
    return z;
}

__device__ __forceinline__ unsigned pk2(float a, float b) {
    union { __bf16 h[2]; unsigned u; } t;
    t.h[0] = (__bf16)a; t.h[1] = (__bf16)b;
    return t.u;
}

__device__ __forceinline__ float fmax3(float a, float b, float c) {
    return fmaxf(fmaxf(a, b), c);   // clang fuses to v_max3_f32
}

__device__ __forceinline__ void load16(const __bf16* __restrict__ p, bf16x8& lo, bf16x8& hi) {
    lo = *(const bf16x8*)p;
    hi = *(const bf16x8*)(p + 8);
}

__device__ __forceinline__ void cvt8(const float* __restrict__ src, __bf16* __restrict__ dst, int i) {
    const float4 a = ((const float4*)src)[i * 2];
    const float4 b = ((const float4*)src)[i * 2 + 1];
    ((bf16x8*)dst)[i] = bf16x8{(__bf16)a.x, (__bf16)a.y, (__bf16)a.z, (__bf16)a.w,
                               (__bf16)b.x, (__bf16)b.y, (__bf16)b.z, (__bf16)b.w};
}

// ---------- kernel 0a: fused fp32->bf16 convert for x, wqkv, wproj ----------
__global__ __launch_bounds__(256) void conv_tri(const float* __restrict__ s1, __bf16* __restrict__ d1, int n1,
                                                const float* __restrict__ s2, __bf16* __restrict__ d2, int n2,
                                                const float* __restrict__ s3, __bf16* __restrict__ d3, int n3) {
    const int i = blockIdx.x * 256 + threadIdx.x;
    if (i < n1)                 cvt8(s1, d1, i);
    else if (i < n1 + n2)       cvt8(s2, d2, i - n1);
    else if (i < n1 + n2 + n3)  cvt8(s3, d3, i - n1 - n2);
}

// ---------- kernel 0b: pair convert (fallback when ws too small for separate Wp) ----------
__global__ __launch_bounds__(256) void conv_pair(const float* __restrict__ s1, __bf16* __restrict__ d1, int n1,
                                                 const float* __restrict__ s2, __bf16* __restrict__ d2, int n2) {
    const int i = blockIdx.x * 256 + threadIdx.x;
    if (i < n1)            cvt8(s1, d1, i);
    else if (i < n1 + n2)  cvt8(s2, d2, i - n1);
}

__global__ __launch_bounds__(256) void conv_bf16(const float* __restrict__ src,
                                                 __bf16* __restrict__ dst, int n8) {
    const int i = blockIdx.x * 256 + threadIdx.x;
    if (i >= n8) return;
    cvt8(src, dst, i);
}

// ---------- shared GEMM core (m97 structure): 128x128 tile, BK=32, global_load_lds ----------
// 64B LDS rows: consecutive rows alternate bank offset 0/16 (8-way max).
__device__ __forceinline__ void gemm_core(const __bf16* __restrict__ A, const __bf16* __restrict__ B,
                                          const int K, const int rowBase, const int colBase,
                                          __bf16* As, __bf16* Bs, f32x4 (&acc)[4][4]) {
    const int tid = threadIdx.x, lane = tid & 63, wid = tid >> 6;
    const int wm = wid >> 1, wn = wid & 1;
    const int lr = lane & 15, lg = lane >> 4;
    const int lrow = lane >> 2, lcol = (lane & 3) * 8;

    const __bf16* aBase = A + (size_t)(rowBase + wid * 16 + lrow) * K + lcol;
    const __bf16* bBase = B + (size_t)(colBase + wid * 16 + lrow) * K + lcol;
    const size_t row64 = (size_t)64 * K;

    for (int kt = 0; kt < K; kt += 32) {
        __syncthreads();
        GLOAD16(aBase + kt,         As + wid * 512);
        GLOAD16(aBase + row64 + kt, As + 2048 + wid * 512);
        GLOAD16(bBase + kt,         Bs + wid * 512);
        GLOAD16(bBase + row64 + kt, Bs + 2048 + wid * 512);
        __syncthreads();

        bf16x8 af[4], bfr[4];
#pragma unroll
        for (int i = 0; i < 4; ++i) {
            af[i]  = *(const bf16x8*)&As[(wm * 64 + i * 16 + lr) * 32 + lg * 8];
            bfr[i] = *(const bf16x8*)&Bs[(wn * 64 + i * 16 + lr) * 32 + lg * 8];
        }
#pragma unroll
        for (int i = 0; i < 4; ++i)
#pragma unroll
            for (int j = 0; j < 4; ++j)
                acc[i][j] = __builtin_amdgcn_mfma_f32_16x16x32_bf16(af[i], bfr[j], acc[i][j], 0, 0, 0);
    }
}

// ---------- kernel 1: QKV projection; Q,K row-major [h][n][d], V transposed+k-slot-permuted ----------
#define QSCALE 0.180336879f   // 1/sqrt(64) * log2(e)

__global__ __launch_bounds__(256) void qkv_gemm(const __bf16* __restrict__ x,
                                                const __bf16* __restrict__ wqkv,
                                                const float* __restrict__ bqkv,
                                                __bf16* __restrict__ Qb,
                                                __bf16* __restrict__ Kb,
                                                __bf16* __restrict__ VtG) {
    __shared__ __bf16 As[128 * 32];
    __shared__ __bf16 Bs[128 * 32];
    f32x4 acc[4][4];
#pragma unroll
    for (int i = 0; i < 4; ++i)
#pragma unroll
        for (int j = 0; j < 4; ++j)
            acc[i][j] = f32x4{0.f, 0.f, 0.f, 0.f};

    // XCD-aware swizzle: 768 blocks, 96/XCD chunk -> B-panel L2 reuse
    const int lin = blockIdx.y * 32 + blockIdx.x;
    const int swz = (lin & 7) * 96 + (lin >> 3);
    const int tm = swz & 31, tn = swz >> 5;

    gemm_core(x, wqkv, E_DIM, tm * 128, tn * 128, As, Bs, acc);

    const int tid = threadIdx.x;
    const int lane = tid & 63, wid = tid >> 6;
    const int wm = wid >> 1, wn = wid & 1;
    const int lr = lane & 15, lg = lane >> 4;

#pragma unroll
    for (int ni = 0; ni < 4; ++ni) {
        const int f = tn * 128 + wn * 64 + ni * 16 + lr;   // 0..3071
        const float bias = bqkv[f];
        const int which = f >> 10;          // 0=Q 1=K 2=V (uniform per block)
        const int hh = (f & 1023) >> 6;
        const int dd = f & 63;
        if (which == 2) {
            __bf16* dst = VtG + ((size_t)hh * HD + dd) * N_TOK;
#pragma unroll
            for (int mi = 0; mi < 4; ++mi) {
                const int n0 = tm * 128 + wm * 64 + mi * 16 + lg * 4;
                const int pos = (n0 & ~12) | ((n0 & 4) << 1) | ((n0 & 8) >> 1);  // swap bits 2,3
                bf16x4 v;
#pragma unroll
                for (int r = 0; r < 4; ++r) v[r] = (__bf16)(acc[mi][ni][r] + bias);
                *(bf16x4*)&dst[pos] = v;
            }
        } else {
            __bf16* dst = (which == 0) ? Qb : Kb;
            const float sc = (which == 0) ? QSCALE : 1.0f;
#pragma unroll
            for (int mi = 0; mi < 4; ++mi) {
#pragma unroll
                for (int r = 0; r < 4; ++r) {
                    const int n = tm * 128 + wm * 64 + mi * 16 + lg * 4 + r;
                    dst[((size_t)hh * N_TOK + n) * HD + dd] = (__bf16)((acc[mi][ni][r] + bias) * sc);
                }
            }
        }
    }
}

// ---------- kernel 2: flash attention (round-14 verified form: LDS-staged, dbuf, no exchange) ----------
#define QBLK  256
#define KVB   128
#define NTILE (N_TOK / KVB)
#define KST   72
#define VST   136
#define BUFSZ (KVB * KST + HD * VST)

__global__ __launch_bounds__(512, 2) void flash_attn(const __bf16* __restrict__ Qb,
                                                     const __bf16* __restrict__ Kb,
                                                     const __bf16* __restrict__ Vt,
                                                     __bf16* __restrict__ Ob) {
    __shared__ __bf16 smem[2 * BUFSZ];   // 71680 B

    const int tid = threadIdx.x, lane = tid & 63, wid = tid >> 6;
    const int lq = lane & 31, hi = lane >> 5;
    const int qg = wid >> 1, hw = wid & 1;

    // XCD swizzle: 256 blocks, 32/XCD = 2 full heads' K/V resident per XCD L2
    const int lin = blockIdx.y * 16 + blockIdx.x;
    const int swz = (lin & 7) * 32 + (lin >> 3);
    const int qblk = swz & 15, h = swz >> 4;

    const __bf16* Qh = Qb + (size_t)h * N_TOK * HD;
    const __bf16* Kh = Kb + (size_t)h * N_TOK * HD;
    const __bf16* Vh = Vt + (size_t)h * HD * N_TOK;

    // Q B-frags for 2 q-subtiles: col=q=lq, k-slot (hi,j): d = sd*16 + hi*8 + j
    bf16x8 qf[2][4];
#pragma unroll
    for (int g = 0; g < 2; ++g) {
        const size_t qr = (size_t)qblk * QBLK + qg * 64 + g * 32 + lq;
#pragma unroll
        for (int sd = 0; sd < 4; ++sd)
            qf[g][sd] = *(const bf16x8*)&Qh[qr * HD + sd * 16 + hi * 8];
    }

    f32x16 o[2][2], lacc[2];
#pragma unroll
    for (int g = 0; g < 2; ++g) { o[g][0] = zero16(); o[g][1] = zero16(); lacc[g] = zero16(); }
    float m[2] = {-INFINITY, -INFINITY};

    const bf16x8 ones = bf16x8{(__bf16)1.f, (__bf16)1.f, (__bf16)1.f, (__bf16)1.f,
                               (__bf16)1.f, (__bf16)1.f, (__bf16)1.f, (__bf16)1.f};

    // staging: K tile 128x64 (4 thr/row), V tile 64x128 (8 thr/row)
    const int krow = tid >> 2, kseg = (tid & 3) * 16;
    const int vrow = tid >> 3, vseg = (tid & 7) * 16;
    const __bf16* kSrc = Kh + (size_t)krow * HD + kseg;
    const __bf16* vSrc = Vh + (size_t)vrow * N_TOK + vseg;

    bf16x8 kr0, kr1, vr0, vr1;
    load16(kSrc, kr0, kr1);
    load16(vSrc, vr0, vr1);
    {   // prologue: tile 0 -> buf 0
        __bf16* Kw = smem;
        __bf16* Vw = smem + KVB * KST;
        *(bf16x8*)&Kw[krow * KST + kseg]     = kr0;
        *(bf16x8*)&Kw[krow * KST + kseg + 8] = kr1;
        *(bf16x8*)&Vw[vrow * VST + vseg]     = vr0;
        *(bf16x8*)&Vw[vrow * VST + vseg + 8] = vr1;
    }

    for (int t = 0; t < NTILE; ++t) {
        const int cur = t & 1;
        const __bf16* Kc = smem + cur * BUFSZ;
        const __bf16* Vc = Kc + KVB * KST;

        if (t + 1 < NTILE) {   // prefetch next tile into regs (hides HBM under compute)
            load16(kSrc + (size_t)(t + 1) * KVB * HD, kr0, kr1);
            load16(vSrc + (t + 1) * KVB, vr0, vr1);
        }
        __syncthreads();   // buf[cur] visible; buf[cur^1] readers done

        // S^T = K Q^T on this wave's 64-kv half, both q-subtiles share each kf read
        f32x16 s[2][2];
#pragma unroll
        for (int g = 0; g < 2; ++g) { s[g][0] = zero16(); s[g][1] = zero16(); }
        __builtin_amdgcn_s_setprio(1);
#pragma unroll
        for (int sd = 0; sd < 4; ++sd) {
            const bf16x8 kf0 = *(const bf16x8*)&Kc[(hw * 64 + lq) * KST + sd * 16 + hi * 8];
            const bf16x8 kf1 = *(const bf16x8*)&Kc[(hw * 64 + 32 + lq) * KST + sd * 16 + hi * 8];
            s[0][0] = __builtin_amdgcn_mfma_f32_32x32x16_bf16(kf0, qf[0][sd], s[0][0], 0, 0, 0);
            s[0][1] = __builtin_amdgcn_mfma_f32_32x32x16_bf16(kf1, qf[0][sd], s[0][1], 0, 0, 0);
            s[1][0] = __builtin_amdgcn_mfma_f32_32x32x16_bf16(kf0, qf[1][sd], s[1][0], 0, 0, 0);
            s[1][1] = __builtin_amdgcn_mfma_f32_32x32x16_bf16(kf1, qf[1][sd], s[1][1], 0, 0, 0);
        }
        __builtin_amdgcn_s_setprio(0);

        // per-q max: 3-ary tree (v_max3) over 32 in-lane values + cross-half shuffle
        float mx[2];
#pragma unroll
        for (int g = 0; g < 2; ++g) {
            const float t0 = fmax3(s[g][0][0],  s[g][0][1],  s[g][0][2]);
            const float t1 = fmax3(s[g][0][3],  s[g][0][4],  s[g][0][5]);
            const float t2 = fmax3(s[g][0][6],  s[g][0][7],  s[g][0][8]);
            const float t3 = fmax3(s[g][0][9],  s[g][0][10], s[g][0][11]);
            const float t4 = fmax3(s[g][0][12], s[g][0][13], s[g][0][14]);
            const float t5 = fmax3(s[g][1][0],  s[g][1][1],  s[g][1][2]);
            const float t6 = fmax3(s[g][1][3],  s[g][1][4],  s[g][1][5]);
            const float t7 = fmax3(s[g][1][6],  s[g][1][7],  s[g][1][8]);
            const float t8 = fmax3(s[g][1][9],  s[g][1][10], s[g][1][11]);
            const float t9 = fmax3(s[g][1][12], s[g][1][13], s[g][1][14]);
            const float u0 = fmax3(t0, t1, s[g][0][15]);
            const float u1 = fmax3(t2, t3, t4);
            const float u2 = fmax3(t5, t6, s[g][1][15]);
            const float u3 = fmax3(t7, t8, t9);
            float a = fmaxf(fmax3(u0, u1, u2), u3);
            mx[g] = fmaxf(a, __shfl_xor(a, 32));
        }

        // defer-max: rescale only when per-tile growth exceeds 2^8
        if (!__all(mx[0] <= m[0] + 8.f && mx[1] <= m[1] + 8.f)) {
#pragma unroll
            for (int g = 0; g < 2; ++g) {
                const float mn = fmaxf(m[g], mx[g]);
                const float al = __builtin_amdgcn_exp2f(m[g] - mn);
                m[g] = mn;
#pragma unroll
                for (int r = 0; r < 16; ++r) { o[g][0][r] *= al; o[g][1][r] *= al; }
                lacc[g][0] *= al;
            }
        }

        // per 16-k window: exp2 + pack own regs directly (V k-slot perm makes this exact)
#pragma unroll
        for (int w = 0; w < 4; ++w) {
            const int rb = (w & 1) * 8;
            const int half = (w < 2) ? 0 : 1;
            bf16x8 pfv[2];
#pragma unroll
            for (int g = 0; g < 2; ++g) {
                union { unsigned u[4]; bf16x8 v; } pf;
                pf.u[0] = pk2(__builtin_amdgcn_exp2f(s[g][half][rb + 0] - m[g]),
                              __builtin_amdgcn_exp2f(s[g][half][rb + 1] - m[g]));
                pf.u[1] = pk2(__builtin_amdgcn_exp2f(s[g][half][rb + 2] - m[g]),
                              __builtin_amdgcn_exp2f(s[g][half][rb + 3] - m[g]));
                pf.u[2] = pk2(__builtin_amdgcn_exp2f(s[g][half][rb + 4] - m[g]),
                              __builtin_amdgcn_exp2f(s[g][half][rb + 5] - m[g]));
                pf.u[3] = pk2(__builtin_amdgcn_exp2f(s[g][half][rb + 6] - m[g]),
                              __builtin_amdgcn_exp2f(s[g][half][rb + 7] - m[g]));
                pfv[g] = pf.v;
            }

            const bf16x8 vf0 = *(const bf16x8*)&Vc[lq * VST + hw * 64 + w * 16 + hi * 8];
            const bf16x8 vf1 = *(const bf16x8*)&Vc[(32 + lq) * VST + hw * 64 + w * 16 + hi * 8];
            __builtin_amdgcn_s_setprio(1);
            o[0][0] = __builtin_amdgcn_mfma_f32_32x32x16_bf16(vf0, pfv[0], o[0][0], 0, 0, 0);
            o[0][1] = __builtin_amdgcn_mfma_f32_32x32x16_bf16(vf1, pfv[0], o[0][1], 0, 0, 0);
            o[1][0] = __builtin_amdgcn_mfma_f32_32x32x16_bf16(vf0, pfv[1], o[1][0], 0, 0, 0);
            o[1][1] = __builtin_amdgcn_mfma_f32_32x32x16_bf16(vf1, pfv[1], o[1][1], 0, 0, 0);
            lacc[0] = __builtin_amdgcn_mfma_f32_32x32x16_bf16(ones, pfv[0], lacc[0], 0, 0, 0);
            lacc[1] = __builtin_amdgcn_mfma_f32_32x32x16_bf16(ones, pfv[1], lacc[1], 0, 0, 0);
            __builtin_amdgcn_s_setprio(0);
        }

        if (t + 1 < NTILE) {   // write prefetched tile into other buffer
            __bf16* Kw = smem + (cur ^ 1) * BUFSZ;
            __bf16* Vw = Kw + KVB * KST;
            *(bf16x8*)&Kw[krow * KST + kseg]     = kr0;
            *(bf16x8*)&Kw[krow * KST + kseg + 8] = kr1;
            *(bf16x8*)&Vw[vrow * VST + vseg]     = vr0;
            *(bf16x8*)&Vw[vrow * VST + vseg + 8] = vr1;
        }
    }

    // ---- merge kv-half pairs through LDS, then epilogue (per q-subtile) ----
    __syncthreads();
    float* scratch = (float*)smem;
    if (hw == 1) {
#pragma unroll
        for (int g = 0; g < 2; ++g) {
            float* po = scratch + (qg * 2 + g) * 2080;
#pragma unroll
            for (int r = 0; r < 16; ++r) {
                const int d0 = (r & 3) + 8 * (r >> 2) + 4 * hi;
                po[lq * 65 + d0]      = o[g][0][r];
                po[lq * 65 + 32 + d0] = o[g][1][r];
            }
            if (hi == 0) {
                float* plm = scratch + 16640 + (qg * 2 + g) * 64;
                plm[lq * 2] = lacc[g][0]; plm[lq * 2 + 1] = m[g];
            }
        }
    }
    __syncthreads();
    if (hw == 0) {
#pragma unroll
        for (int g = 0; g < 2; ++g) {
            float* po  = scratch + (qg * 2 + g) * 2080;
            float* plm = scratch + 16640 + (qg * 2 + g) * 64;
            const float l1 = plm[lq * 2], m1 = plm[lq * 2 + 1];
            const float M  = fmaxf(m[g], m1);
            const float a0 = __builtin_amdgcn_exp2f(m[g] - M);
            const float a1 = __builtin_amdgcn_exp2f(m1 - M);
            const float inv = 1.0f / (lacc[g][0] * a0 + l1 * a1);
            const size_t qr = (size_t)qblk * QBLK + qg * 64 + g * 32 + lq;
            __bf16* obase = &Ob[qr * E_DIM + h * HD];
#pragma unroll
            for (int grp = 0; grp < 4; ++grp) {
                bf16x4 v0, v1;
#pragma unroll
                for (int c = 0; c < 4; ++c) {
                    const int r = grp * 4 + c;
                    const int d0 = c + 8 * grp + 4 * hi;
                    v0[c] = (__bf16)((o[g][0][r] * a0 + po[lq * 65 + d0]      * a1) * inv);
                    v1[c] = (__bf16)((o[g][1][r] * a0 + po[lq * 65 + 32 + d0] * a1) * inv);
                }
                *(bf16x4*)&obase[grp * 8 + hi * 4]      = v0;
                *(bf16x4*)&obase[32 + grp * 8 + hi * 4] = v1;
            }
        }
    }
}

// ---------- kernel 3: output projection, 64x128 tile, 512 blocks = 2/CU ----------
__global__ __launch_bounds__(256) void proj_gemm(const __bf16* __restrict__ Ob,
                                                 const __bf16* __restrict__ wp,
                                                 const float* __restrict__ bp,
                                                 float* __restrict__ out) {
    __shared__ __bf16 As[64 * 32];
    __shared__ __bf16 Bs[128 * 32];
    f32x4 acc[2][4];
#pragma unroll
    for (int i = 0; i < 2; ++i)
#pragma unroll
        for (int j = 0; j < 4; ++j)
            acc[i][j] = f32x4{0.f, 0.f, 0.f, 0.f};

    // XCD swizzle: 512 blocks, 64/XCD -> tn constant per XCD (B panel L2-resident)
    const int lin = blockIdx.y * 64 + blockIdx.x;
    const int swz = (lin & 7) * 64 + (lin >> 3);
    const int tm = swz & 63, tn = swz >> 6;

    const int tid = threadIdx.x, lane = tid & 63, wid = tid >> 6;
    const int wm = wid >> 1, wn = wid & 1;
    const int lr = lane & 15, lg = lane >> 4;
    const int lrow = lane >> 2, lcol = (lane & 3) * 8;

    const __bf16* aBase = Ob + (size_t)(tm * 64 + wid * 16 + lrow) * E_DIM + lcol;
    const __bf16* bBase = wp + (size_t)(tn * 128 + wid * 16 + lrow) * E_DIM + lcol;
    const size_t row64 = (size_t)64 * E_DIM;

    for (int kt = 0; kt < E_DIM; kt += 32) {
        __syncthreads();
        GLOAD16(aBase + kt,         As + wid * 512);
        GLOAD16(bBase + kt,         Bs + wid * 512);
        GLOAD16(bBase + row64 + kt, Bs + 2048 + wid * 512);
        __syncthreads();

        bf16x8 af[2], bfr[4];
#pragma unroll
        for (int i = 0; i < 2; ++i)
            af[i]  = *(const bf16x8*)&As[(wm * 32 + i * 16 + lr) * 32 + lg * 8];
#pragma unroll
        for (int j = 0; j < 4; ++j)
            bfr[j] = *(const bf16x8*)&Bs[(wn * 64 + j * 16 + lr) * 32 + lg * 8];
#pragma unroll
        for (int i = 0; i < 2; ++i)
#pragma unroll
            for (int j = 0; j < 4; ++j)
                acc[i][j] = __builtin_amdgcn_mfma_f32_16x16x32_bf16(af[i], bfr[j], acc[i][j], 0, 0, 0);
    }

#pragma unroll
    for (int ni = 0; ni < 4; ++ni) {
        const int f = tn * 128 + wn * 64 + ni * 16 + lr;
        const float bias = bp[f];
#pragma unroll
        for (int mi = 0; mi < 2; ++mi) {
#pragma unroll
            for (int r = 0; r < 4; ++r) {
                const int n = tm * 64 + wm * 32 + mi * 16 + lg * 4 + r;
                out[(size_t)n * E_DIM + f] = acc[mi][ni][r] + bias;
            }
        }
    }
}

// ---------- launch ----------
extern "C" void kernel_launch(void* const* d_in, const int* in_sizes, int n_in,
                              void* d_out, int out_size, void* d_ws, size_t ws_size,
                              hipStream_t stream) {
    const float* x     = (const float*)d_in[0];
    const float* wqkv  = (const float*)d_in[1];
    const float* bqkv  = (const float*)d_in[2];
    const float* wproj = (const float*)d_in[3];
    const float* bproj = (const float*)d_in[4];
    float* out = (float*)d_out;

    const size_t headElems = (size_t)NH * N_TOK * HD;      // 4.19M
    __bf16* Qb   = (__bf16*)d_ws;
    __bf16* Kb   = Qb + headElems;
    __bf16* VtG  = Kb + headElems;                         // [H][D][N'] (k-slot-permuted cols)
    __bf16* ObXb = VtG + headElems;                        // xb during qkv, then Ob
    __bf16* Wb   = ObXb + headElems;                       // wqkv-bf16 (3M elems)

    const int n1 = N_TOK * E_DIM / 8;           // 524288 (x)
    const int n2 = 3 * E_DIM * E_DIM / 8;       // 393216 (wqkv)
    const int n3 = E_DIM * E_DIM / 8;           // 131072 (wproj)

    const size_t needBytes = (4 * headElems + (size_t)(3 + 1) * E_DIM * E_DIM) * sizeof(__bf16);
    const bool sep = ws_size >= needBytes;
    __bf16* Wp = sep ? (Wb + (size_t)3 * E_DIM * E_DIM) : Wb;

    if (sep) {
        conv_tri<<<(n1 + n2 + n3 + 255) / 256, 256, 0, stream>>>(x, ObXb, n1, wqkv, Wb, n2, wproj, Wp, n3);
    } else {
        conv_pair<<<(n1 + n2 + 255) / 256, 256, 0, stream>>>(x, ObXb, n1, wqkv, Wb, n2);
    }

    qkv_gemm<<<dim3(N_TOK / 128, 3 * E_DIM / 128), 256, 0, stream>>>(ObXb, Wb, bqkv, Qb, Kb, VtG);

    if (!sep) {
        conv_bf16<<<(n3 + 255) / 256, 256, 0, stream>>>(wproj, Wp, n3);
    }

    flash_attn<<<dim3(N_TOK / QBLK, NH), 512, 0, stream>>>(Qb, Kb, VtG, ObXb);

    proj_gemm<<<dim3(N_TOK / 64, E_DIM / 128), 256, 0, stream>>>(ObXb, Wp, bproj, out);
}